// Round 6
// baseline (258.350 us; speedup 1.0000x reference)
//
#include <hip/hip_runtime.h>

// DualTimeConstantHighPassMixAdaptation on MI355X (gfx950)
// x: [B=8, C=64, T=64000] fp32. 512 independent dual-EMA scans along T.
//
// R9: global_load_lds double-buffer — make the prefetch REAL.
// Key realization: R6/R8's VGPR_Count=40 cannot contain the 25-VGPR
// prefetch batch -> the scheduler SANK the "prefetch" loads to just
// before the commit (nothing pinned their issue point). Every tile paid
// full congested memory latency serially: 10.2us/tile wall vs ~1.5us of
// compute, VALUBusy 26%. Cross-round evidence: R3 (VGPR=80, real
// prefetch, 8 waves/CU) == R6 (no prefetch, 16 waves/CU) == ~91us;
// R4's spill traffic accidentally raised delivered BW to 3.24 TB/s ->
// the memory system has headroom when outstanding bytes stay up.
// Fix: depth-1 prefetch via __builtin_amdgcn_global_load_lds (async
// global->LDS, zero VGPRs, can't be sunk past its explicit vmcnt wait):
//  - 2 LDS tile buffers per wave (12.8 KB); stage tile t+1 into buf^1
//    while computing buf; outputs overwrite the consumed buffer in place.
//  - Counted waits: after an emitting tile, wait vmcnt(7) (the 7 stores
//    are FIFO-newer than the 25 gll dwords -> stores get a full tile of
//    drain slack, never serialize); after halo tiles wait vmcnt(0).
//  - No ds_write commit at all; no prefetch registers -> ~40 VGPR, no
//    spill risk, allocator can't sabotage.
//  - WPB=2 (128 thr), 2048 blocks, 25.6 KB/block -> 6 blocks/CU =
//    12 waves/CU, each with a full tile ALWAYS in flight (full duty).

#define THREADS 128
#define WPB 2                     // waves per block
#define K 25                      // floats per lane per tile (gcd(25,32)=1: LDS-conflict-free)
#define WTILE (64 * K)            // 1600 floats = 6.4 KB per wave-tile
#define T_LEN 64000
#define SEGS_W 8
#define SEG_LEN (T_LEN / SEGS_W)  // 8000 floats
#define SEG_TILES (SEG_LEN / WTILE) // 5
#define HALO_TILES 4              // 6400-sample halo (a_slow^6400 ~ 1.3e-3)
#define EPS_V 1e-6f

typedef float nfloat4 __attribute__((ext_vector_type(4)));  // native vec for nt builtins

// force a wave-uniform float into an SGPR
__device__ __forceinline__ float rfl(float v) {
    return __int_as_float(__builtin_amdgcn_readfirstlane(__float_as_int(v)));
}

// async global->LDS dword: per-lane global src, wave-uniform LDS dst + lane*4
__device__ __forceinline__ void gll_dword(const float* g, float* l) {
    __builtin_amdgcn_global_load_lds(
        (const __attribute__((address_space(1))) unsigned int*)g,
        (__attribute__((address_space(3))) unsigned int*)l,
        4, 0, 0);
}

// stage one 1600-float tile: 25 gll dwords (op c covers floats [c*64, c*64+64))
__device__ __forceinline__ void stage(const float* gt, float* b, int lane) {
#pragma unroll
    for (int c = 0; c < K; ++c)
        gll_dword(gt + c * 64 + lane, b + c * 64);
}

__global__ __launch_bounds__(THREADS, 2)
void dual_ema_hp_kernel(const float* __restrict__ x,
                        const float* __restrict__ p_mu_fast,
                        const float* __restrict__ p_mu_slow,
                        const float* __restrict__ p_mwa,
                        const float* __restrict__ p_mhp,
                        float* __restrict__ out)
{
    __shared__ __align__(16) float lds[WPB * 2 * WTILE];   // 25.6 KB/block
    const int tid  = threadIdx.x;
    const int lane = tid & 63;
    const int wv   = tid >> 6;
    float* buf0 = &lds[wv * 2 * WTILE];
    float* buf1 = buf0 + WTILE;

    const int gw  = blockIdx.x * WPB + wv;
    const int row = gw / SEGS_W;
    const int seg = gw % SEGS_W;
    const int h   = (seg == 0) ? 0 : HALO_TILES;
    const int nt  = SEG_TILES + h;

    const float* gseg = x   + (size_t)row * T_LEN + (size_t)seg * SEG_LEN - (size_t)h * WTILE;
    float*       oseg = out + (size_t)row * T_LEN + (size_t)seg * SEG_LEN - (size_t)h * WTILE;

    // ---- wave-uniform constants -> SGPRs ----
    const float mu_f = rfl(p_mu_fast[0]);
    const float mu_s = rfl(p_mu_slow[0]);
    const float af = rfl(1.0f - mu_f);
    const float as = rfl(1.0f - mu_s);
    const float wa  = rfl(1.0f / (1.0f + __expf(-p_mwa[0])));   // sigmoid(mwa)
    const float wb  = rfl(1.0f - wa);
    const float whp = rfl(1.0f / (1.0f + __expf(-p_mhp[0])));   // sigmoid(mhp)

    // chunk decay (25 samples) + powers for the shfl_up scan
    const float Pf1  = rfl(__powf(af, (float)K));
    const float Ps1  = rfl(__powf(as, (float)K));
    const float Pf2  = rfl(Pf1 * Pf1),   Ps2  = rfl(Ps1 * Ps1);
    const float Pf4  = rfl(Pf2 * Pf2),   Ps4  = rfl(Ps2 * Ps2);
    const float Pf8  = rfl(Pf4 * Pf4),   Ps8  = rfl(Ps4 * Ps4);
    const float Pf16 = rfl(Pf8 * Pf8),   Ps16 = rfl(Ps8 * Ps8);
    const float Pf32 = rfl(Pf16 * Pf16), Ps32 = rfl(Ps16 * Ps16);

    // ---- prologue: async-stage tiles 0 and 1 (nt >= 5 always) ----
    stage(gseg, buf0, lane);
    stage(gseg + WTILE, buf1, lane);
    asm volatile("s_waitcnt vmcnt(25)" ::: "memory");   // tile 0 landed (tile 1's 25 may fly)

    float sfr = 0.0f, ssr = 0.0f;   // wave's carried EMA state (zero at halo start)

    for (int t = 0; t < nt; ++t) {
        float* buf = (t & 1) ? buf1 : buf0;

        // ---- wait for tile t's gll dwords to land ----
        // If tile t-1 emitted stores (t > h), those 7 stores are FIFO-newer
        // than gll_t: vmcnt(7) completes gll_t while stores keep draining.
        // Halo tiles (t <= h, t > 0) have no stores in flight: drain to 0.
        if (t > h)       { asm volatile("s_waitcnt vmcnt(7)" ::: "memory"); }
        else if (t > 0)  { asm volatile("s_waitcnt vmcnt(0)" ::: "memory"); }
        // t == 0: prologue already waited vmcnt(25).

        // first sample of the whole row: init-at-first-sample == seed y0
        if (seg == 0 && t == 0 && lane == 0) {
            float y0 = fmaxf(buf[0], 0.0f);
            sfr = y0; ssr = y0;
        }

        // ---- issue async stage for tile t+1 into the other buffer ----
        // (t=0's next tile was staged in the prologue; the other buffer's
        //  consumers -- tile t-1's reads/readback -- completed last tile.)
        if (t >= 1 && t + 1 < nt)
            stage(gseg + (size_t)(t + 1) * WTILE, (t & 1) ? buf0 : buf1, lane);

        // ---- phase 1: per-lane local scan, streamed from LDS ----
        float inf = (lane == 0) ? sfr : 0.0f;
        float ins = (lane == 0) ? ssr : 0.0f;
        float mf, ms;
        {
            float yv = fmaxf(buf[lane * K], 0.0f);   // stride 25: 2-way alias, free
            mf = fmaf(af, inf, mu_f * yv);
            ms = fmaf(as, ins, mu_s * yv);
        }
#pragma unroll
        for (int i = 1; i < K; ++i) {
            float yv = fmaxf(buf[lane * K + i], 0.0f);
            mf = fmaf(af, mf, mu_f * yv);
            ms = fmaf(as, ms, mu_s * yv);
        }

        // ---- wave inclusive scan of carries: S_l = c_l + P * S_{l-1} ----
        float cf = mf, cs = ms, uf, us;
        uf = __shfl_up(cf, 1);  us = __shfl_up(cs, 1);
        cf = (lane >= 1)  ? fmaf(Pf1,  uf, cf) : cf;  cs = (lane >= 1)  ? fmaf(Ps1,  us, cs) : cs;
        uf = __shfl_up(cf, 2);  us = __shfl_up(cs, 2);
        cf = (lane >= 2)  ? fmaf(Pf2,  uf, cf) : cf;  cs = (lane >= 2)  ? fmaf(Ps2,  us, cs) : cs;
        uf = __shfl_up(cf, 4);  us = __shfl_up(cs, 4);
        cf = (lane >= 4)  ? fmaf(Pf4,  uf, cf) : cf;  cs = (lane >= 4)  ? fmaf(Ps4,  us, cs) : cs;
        uf = __shfl_up(cf, 8);  us = __shfl_up(cs, 8);
        cf = (lane >= 8)  ? fmaf(Pf8,  uf, cf) : cf;  cs = (lane >= 8)  ? fmaf(Ps8,  us, cs) : cs;
        uf = __shfl_up(cf, 16); us = __shfl_up(cs, 16);
        cf = (lane >= 16) ? fmaf(Pf16, uf, cf) : cf;  cs = (lane >= 16) ? fmaf(Ps16, us, cs) : cs;
        uf = __shfl_up(cf, 32); us = __shfl_up(cs, 32);
        cf = (lane >= 32) ? fmaf(Pf32, uf, cf) : cf;  cs = (lane >= 32) ? fmaf(Ps32, us, cs) : cs;

        // exclusive value = state entering my chunk; lane0 <- carried state
        float ex_f = __shfl_up(cf, 1), ex_s = __shfl_up(cs, 1);
        if (lane == 0) { ex_f = sfr; ex_s = ssr; }
        // state after this tile (broadcast from lane 63)
        sfr = __shfl(cf, 63);
        ssr = __shfl(cs, 63);

        // CSE barrier: forces phase 2 to re-read LDS instead of keeping 25
        // values live across the scan (keeps VGPR ~40). lgkm queue empty -> free.
        asm volatile("s_waitcnt lgkmcnt(0)" ::: "memory");

        const bool emit = (t >= h);
        if (emit) {
            // ---- phase 2: re-scan with correct state, outputs in place ----
            float mf2 = ex_f, ms2 = ex_s;
#pragma unroll
            for (int i = 0; i < K; ++i) {
                float yv = fmaxf(buf[lane * K + i], 0.0f);
                mf2 = fmaf(af, mf2, mu_f * yv);
                ms2 = fmaf(as, ms2, mu_s * yv);
                float M = fmaf(wa, mf2, wb * ms2);
                float o = yv * __builtin_amdgcn_rcpf(EPS_V + M) + whp * (yv - M);
                buf[lane * K + i] = o;                 // overwrite consumed input
            }
            asm volatile("s_waitcnt lgkmcnt(0)" ::: "memory");  // cross-lane flush

            // ---- read-back + nt store (7 VMEM stores, FIFO-newer than
            //      the gll dwords of tile t+1 issued above) ----
            float* gout = oseg + (size_t)t * WTILE;
            nfloat4* go4 = (nfloat4*)gout;
            const nfloat4* o4 = (const nfloat4*)buf;
#pragma unroll
            for (int c = 0; c < 6; ++c) {
                nfloat4 v = o4[c * 64 + lane];
                __builtin_nontemporal_store(v, &go4[c * 64 + lane]);
            }
            __builtin_nontemporal_store(buf[1536 + lane], &gout[1536 + lane]);
        }
    }
}

extern "C" void kernel_launch(void* const* d_in, const int* in_sizes, int n_in,
                              void* d_out, int out_size, void* d_ws, size_t ws_size,
                              hipStream_t stream) {
    const float* x    = (const float*)d_in[0];
    const float* mu_f = (const float*)d_in[1];
    const float* mu_s = (const float*)d_in[2];
    const float* mwa  = (const float*)d_in[3];
    const float* mhp  = (const float*)d_in[4];
    float* out = (float*)d_out;

    const int rows   = in_sizes[0] / T_LEN;          // 512
    const int blocks = rows * SEGS_W / WPB;          // 2048
    dual_ema_hp_kernel<<<blocks, THREADS, 0, stream>>>(x, mu_f, mu_s, mwa, mhp, out);
}

// Round 7
// 249.466 us; speedup vs baseline: 1.0356x; 1.0356x over previous
//
#include <hip/hip_runtime.h>

// DualTimeConstantHighPassMixAdaptation on MI355X (gfx950)
// x: [B=8, C=64, T=64000] fp32. 512 independent dual-EMA scans along T.
//
// R10: depth-2 async pipeline — the latency is 4x the compute, so depth-1
// prefetch (R3/R6/R9, all ~91us) can never hide it.
// Evidence: R3 (298 MB demand) == R6 (364 MB) == 91us -> NOT byte-bound;
// per-tile wall ~10us == chip-wide outstanding (~40MB) / delivered BW
// (~4 TB/s) = loaded queue latency; compute is only ~2.4us/tile.
// Changes vs R9:
//  - 3 LDS buffers/wave (19.2 KB): tiles t+1, t+2 in flight while
//    computing t -> wait at t is for data requested ~2 compute-phases
//    earlier. Counted waits: steady vmcnt(14) = leave [gll(t+1), st(t-1)];
//    halo/first/last vmcnt(7).
//  - gll width 16B: 6x dwordx4 + 1x dword = 7 VMEM instrs/tile (was 25).
//  - SEGS_W=4: halo amortized over 10 tiles (read amp 1.3x, -18% bytes).
//  - WPB=2, grid 1024 = EXACTLY 4 blocks/CU x 256 CU -> zero tail
//    (R9's 2048 vs 1536-capacity had a 33% second pass).
// Kept: wave-autonomous zero-barrier structure, K=25 stride (conflict-free),
// phase2 re-reads LDS (keeps VGPR low), SGPR-pinned constants, nt stores.

#define THREADS 128
#define WPB 2                     // waves per block
#define K 25                      // floats per lane per tile
#define WTILE (64 * K)            // 1600 floats = 6.4 KB per wave-tile
#define NBUF 3                    // depth-2 pipeline: 2 in flight + 1 computing
#define T_LEN 64000
#define SEGS_W 4
#define SEG_LEN (T_LEN / SEGS_W)  // 16000 floats
#define SEG_TILES (SEG_LEN / WTILE) // 10
#define HALO_TILES 4              // 6400-sample halo (a_slow^6400 ~ 1.3e-3)
#define EPS_V 1e-6f

typedef float nfloat4 __attribute__((ext_vector_type(4)));  // native vec for nt builtins

// force a wave-uniform float into an SGPR
__device__ __forceinline__ float rfl(float v) {
    return __int_as_float(__builtin_amdgcn_readfirstlane(__float_as_int(v)));
}

// async-stage one 1600-float tile: 6 x 16B/lane + 1 x 4B/lane global->LDS.
// LDS dst is wave-uniform base + lane*width (linear); global src per-lane.
__device__ __forceinline__ void stage(const float* gt, float* b, int lane) {
#pragma unroll
    for (int c = 0; c < 6; ++c)
        __builtin_amdgcn_global_load_lds(
            (const __attribute__((address_space(1))) unsigned int*)(gt + c * 256 + lane * 4),
            (__attribute__((address_space(3))) unsigned int*)(b + c * 256),
            16, 0, 0);
    __builtin_amdgcn_global_load_lds(
        (const __attribute__((address_space(1))) unsigned int*)(gt + 1536 + lane),
        (__attribute__((address_space(3))) unsigned int*)(b + 1536),
        4, 0, 0);
}

__global__ __launch_bounds__(THREADS, 2)
void dual_ema_hp_kernel(const float* __restrict__ x,
                        const float* __restrict__ p_mu_fast,
                        const float* __restrict__ p_mu_slow,
                        const float* __restrict__ p_mwa,
                        const float* __restrict__ p_mhp,
                        float* __restrict__ out)
{
    __shared__ __align__(16) float lds[WPB * NBUF * WTILE];   // 38.4 KB/block -> 4 blocks/CU
    const int tid  = threadIdx.x;
    const int lane = tid & 63;
    const int wv   = tid >> 6;
    float* bufs = &lds[wv * NBUF * WTILE];

    const int gw  = blockIdx.x * WPB + wv;
    const int row = gw / SEGS_W;
    const int seg = gw % SEGS_W;
    const int h   = (seg == 0) ? 0 : HALO_TILES;
    const int nt  = SEG_TILES + h;

    const float* gseg = x   + (size_t)row * T_LEN + (size_t)seg * SEG_LEN - (size_t)h * WTILE;
    float*       oseg = out + (size_t)row * T_LEN + (size_t)seg * SEG_LEN - (size_t)h * WTILE;

    // ---- wave-uniform constants -> SGPRs ----
    const float mu_f = rfl(p_mu_fast[0]);
    const float mu_s = rfl(p_mu_slow[0]);
    const float af = rfl(1.0f - mu_f);
    const float as = rfl(1.0f - mu_s);
    const float wa  = rfl(1.0f / (1.0f + __expf(-p_mwa[0])));   // sigmoid(mwa)
    const float wb  = rfl(1.0f - wa);
    const float whp = rfl(1.0f / (1.0f + __expf(-p_mhp[0])));   // sigmoid(mhp)

    // chunk decay (25 samples) + powers for the shfl_up scan
    const float Pf1  = rfl(__powf(af, (float)K));
    const float Ps1  = rfl(__powf(as, (float)K));
    const float Pf2  = rfl(Pf1 * Pf1),   Ps2  = rfl(Ps1 * Ps1);
    const float Pf4  = rfl(Pf2 * Pf2),   Ps4  = rfl(Ps2 * Ps2);
    const float Pf8  = rfl(Pf4 * Pf4),   Ps8  = rfl(Ps4 * Ps4);
    const float Pf16 = rfl(Pf8 * Pf8),   Ps16 = rfl(Ps8 * Ps8);
    const float Pf32 = rfl(Pf16 * Pf16), Ps32 = rfl(Ps16 * Ps16);

    // ---- prologue: async-stage tiles 0 and 1 (nt >= 10 always) ----
    stage(gseg,         bufs + 0 * WTILE, lane);
    stage(gseg + WTILE, bufs + 1 * WTILE, lane);

    float sfr = 0.0f, ssr = 0.0f;   // wave's carried EMA state (zero at halo start)

    for (int t = 0; t < nt; ++t) {
        float* buf = bufs + (t % NBUF) * WTILE;

        // ---- wait for tile t's 7 gll ops to land ----
        // Steady state (t>h, t<nt-1): outstanding = [gll(t)7, st(t-2)<=7,
        // gll(t+1)7, st(t-1)7] -> vmcnt(14) completes gll(t)+st(t-2),
        // leaves [gll(t+1), st(t-1)]. Otherwise (halo: no stores in
        // flight; first/last tiles): outstanding <= gll(t)+gll(t+1)+st = 21,
        // vmcnt(7) completes gll(t), leaves at most the newest 7.
        if (t > h && t < nt - 1) { asm volatile("s_waitcnt vmcnt(14)" ::: "memory"); }
        else                     { asm volatile("s_waitcnt vmcnt(7)"  ::: "memory"); }

        // ---- issue async stage for tile t+2 into the retired buffer ----
        // (buf[(t+2)%NBUF] = buf[(t-1)%NBUF]: its readback ds_reads completed
        //  at end of iter t-1, stores captured data into VGPRs before issue.)
        if (t + 2 < nt)
            stage(gseg + (size_t)(t + 2) * WTILE, bufs + ((t + 2) % NBUF) * WTILE, lane);

        // first sample of the whole row: init-at-first-sample == seed y0
        if (seg == 0 && t == 0 && lane == 0) {
            float y0 = fmaxf(buf[0], 0.0f);
            sfr = y0; ssr = y0;
        }

        // ---- phase 1: per-lane local scan, streamed from LDS ----
        float inf = (lane == 0) ? sfr : 0.0f;
        float ins = (lane == 0) ? ssr : 0.0f;
        float mf, ms;
        {
            float yv = fmaxf(buf[lane * K], 0.0f);   // stride 25: 2-way alias, free
            mf = fmaf(af, inf, mu_f * yv);
            ms = fmaf(as, ins, mu_s * yv);
        }
#pragma unroll
        for (int i = 1; i < K; ++i) {
            float yv = fmaxf(buf[lane * K + i], 0.0f);
            mf = fmaf(af, mf, mu_f * yv);
            ms = fmaf(as, ms, mu_s * yv);
        }

        // ---- wave inclusive scan of carries: S_l = c_l + P * S_{l-1} ----
        float cf = mf, cs = ms, uf, us;
        uf = __shfl_up(cf, 1);  us = __shfl_up(cs, 1);
        cf = (lane >= 1)  ? fmaf(Pf1,  uf, cf) : cf;  cs = (lane >= 1)  ? fmaf(Ps1,  us, cs) : cs;
        uf = __shfl_up(cf, 2);  us = __shfl_up(cs, 2);
        cf = (lane >= 2)  ? fmaf(Pf2,  uf, cf) : cf;  cs = (lane >= 2)  ? fmaf(Ps2,  us, cs) : cs;
        uf = __shfl_up(cf, 4);  us = __shfl_up(cs, 4);
        cf = (lane >= 4)  ? fmaf(Pf4,  uf, cf) : cf;  cs = (lane >= 4)  ? fmaf(Ps4,  us, cs) : cs;
        uf = __shfl_up(cf, 8);  us = __shfl_up(cs, 8);
        cf = (lane >= 8)  ? fmaf(Pf8,  uf, cf) : cf;  cs = (lane >= 8)  ? fmaf(Ps8,  us, cs) : cs;
        uf = __shfl_up(cf, 16); us = __shfl_up(cs, 16);
        cf = (lane >= 16) ? fmaf(Pf16, uf, cf) : cf;  cs = (lane >= 16) ? fmaf(Ps16, us, cs) : cs;
        uf = __shfl_up(cf, 32); us = __shfl_up(cs, 32);
        cf = (lane >= 32) ? fmaf(Pf32, uf, cf) : cf;  cs = (lane >= 32) ? fmaf(Ps32, us, cs) : cs;

        // exclusive value = state entering my chunk; lane0 <- carried state
        float ex_f = __shfl_up(cf, 1), ex_s = __shfl_up(cs, 1);
        if (lane == 0) { ex_f = sfr; ex_s = ssr; }
        // state after this tile (broadcast from lane 63)
        sfr = __shfl(cf, 63);
        ssr = __shfl(cs, 63);

        // CSE barrier: forces phase 2 to re-read LDS instead of keeping 25
        // values live across the scan (keeps VGPR low). lgkm queue empty -> free.
        asm volatile("s_waitcnt lgkmcnt(0)" ::: "memory");

        const bool emit = (t >= h);
        if (emit) {
            // ---- phase 2: re-scan with correct state, outputs in place ----
            float mf2 = ex_f, ms2 = ex_s;
#pragma unroll
            for (int i = 0; i < K; ++i) {
                float yv = fmaxf(buf[lane * K + i], 0.0f);
                mf2 = fmaf(af, mf2, mu_f * yv);
                ms2 = fmaf(as, ms2, mu_s * yv);
                float M = fmaf(wa, mf2, wb * ms2);
                float o = yv * __builtin_amdgcn_rcpf(EPS_V + M) + whp * (yv - M);
                buf[lane * K + i] = o;                 // overwrite consumed input
            }
            asm volatile("s_waitcnt lgkmcnt(0)" ::: "memory");  // cross-lane flush

            // ---- read-back + nt store (7 VMEM stores, FIFO-newer than the
            //      gll ops of tile t+2 issued above) ----
            float* gout = oseg + (size_t)t * WTILE;
            nfloat4* go4 = (nfloat4*)gout;
            const nfloat4* o4 = (const nfloat4*)buf;
#pragma unroll
            for (int c = 0; c < 6; ++c) {
                nfloat4 v = o4[c * 64 + lane];
                __builtin_nontemporal_store(v, &go4[c * 64 + lane]);
            }
            __builtin_nontemporal_store(buf[1536 + lane], &gout[1536 + lane]);
        }
    }
}

extern "C" void kernel_launch(void* const* d_in, const int* in_sizes, int n_in,
                              void* d_out, int out_size, void* d_ws, size_t ws_size,
                              hipStream_t stream) {
    const float* x    = (const float*)d_in[0];
    const float* mu_f = (const float*)d_in[1];
    const float* mu_s = (const float*)d_in[2];
    const float* mwa  = (const float*)d_in[3];
    const float* mhp  = (const float*)d_in[4];
    float* out = (float*)d_out;

    const int rows   = in_sizes[0] / T_LEN;          // 512
    const int blocks = rows * SEGS_W / WPB;          // 1024 = 4 blocks/CU exactly
    dual_ema_hp_kernel<<<blocks, THREADS, 0, stream>>>(x, mu_f, mu_s, mwa, mhp, out);
}